// Round 16
// baseline (192.413 us; speedup 1.0000x reference)
//
#include <hip/hip_runtime.h>
#include <math.h>

// Problem constants
static constexpr int B_ = 8, L_ = 1024, D_ = 64, H_ = 16, DH_ = 4, DFF_ = 256;
static constexpr int M_ = B_ * L_;          // 8192 rows
static constexpr float EPS_ = 1e-5f;
static constexpr float INV_N_ = 1.0f / (float)M_;   // BN normalizer
static constexpr int PSTR_ = 512;           // parts row stride (max producer blocks)

typedef _Float16 half4_ __attribute__((ext_vector_type(4)));
typedef __fp16   fp16x2 __attribute__((ext_vector_type(2)));
typedef float    f32x4  __attribute__((ext_vector_type(4)));

// ---------------------------------------------------------------------------
// Embed (+ weight prep side job): C = x @ W_embed^T + bias, stats epilogue.
// C^T MFMA convention: acc[nt] reg r at lane (g,ml) = C[m0+w*16+ml][nt*16+4g+r].
// Side job: convert wq,wk,wv,w1,w2 (45056 f32) to f16 into wdst.
// ---------------------------------------------------------------------------
__global__ __launch_bounds__(256) void embed_kernel(
    const float* __restrict__ x, const float* __restrict__ W_embed,
    const float* __restrict__ wq, const float* __restrict__ wk,
    const float* __restrict__ wv, const float* __restrict__ w1,
    const float* __restrict__ w2, const float* __restrict__ bias,
    float* __restrict__ C, float* __restrict__ outParts,
    _Float16* __restrict__ wdst)
{
    const int t = threadIdx.x;
    {   // weight conversion side job (2 elems/thread, 128 blocks x 256 thr)
        int base = (blockIdx.x * 256 + t) * 2;
        #pragma unroll
        for (int i = 0; i < 2; ++i) {
            int e = base + i;
            if (e < 45056) {
                float v;
                if      (e <  4096) v = wq[e];
                else if (e <  8192) v = wk[e - 4096];
                else if (e < 12288) v = wv[e - 8192];
                else if (e < 28672) v = w1[e - 12288];
                else                v = w2[e - 28672];
                wdst[e] = (_Float16)v;
            }
        }
    }

    __shared__ half4_ Alds[64][17];
    __shared__ half4_ Wlds[64][17];
    __shared__ float  wstats[4][128];
    const int m0 = blockIdx.x * 64;

    #pragma unroll
    for (int i = 0; i < 4; ++i) {
        int l = i * 256 + t;
        int row = l >> 4, c4 = l & 15;
        float4 av = *(const float4*)&x[(size_t)(m0 + row) * 64 + c4 * 4];
        Alds[row][c4] = half4_{(_Float16)av.x, (_Float16)av.y,
                               (_Float16)av.z, (_Float16)av.w};
        float4 wv4 = *(const float4*)&W_embed[(size_t)row * 64 + c4 * 4];
        Wlds[row][c4] = half4_{(_Float16)wv4.x, (_Float16)wv4.y,
                               (_Float16)wv4.z, (_Float16)wv4.w};
    }
    __syncthreads();

    const int lane = t & 63, w = t >> 6, g = lane >> 4, ml = lane & 15;

    f32x4 acc[4] = {};
    #pragma unroll
    for (int kci = 0; kci < 4; ++kci) {
        half4_ af = Alds[w * 16 + ml][kci * 4 + g];
        #pragma unroll
        for (int nt = 0; nt < 4; ++nt) {
            half4_ wf = Wlds[nt * 16 + ml][kci * 4 + g];
            acc[nt] = __builtin_amdgcn_mfma_f32_16x16x16f16(wf, af, acc[nt], 0, 0, 0);
        }
    }

    const int m = m0 + w * 16 + ml;
    float sv[4][4], qv[4][4];
    #pragma unroll
    for (int nt = 0; nt < 4; ++nt) {
        const int nc = nt * 16 + 4 * g;
        float4 bv4 = *(const float4*)&bias[nc];
        float r0 = acc[nt][0] + bv4.x, r1 = acc[nt][1] + bv4.y;
        float r2 = acc[nt][2] + bv4.z, r3 = acc[nt][3] + bv4.w;
        float4 o4 = { r0, r1, r2, r3 };
        *(float4*)&C[(size_t)m * 64 + nc] = o4;
        sv[nt][0] = r0; sv[nt][1] = r1; sv[nt][2] = r2; sv[nt][3] = r3;
        qv[nt][0] = r0 * r0; qv[nt][1] = r1 * r1;
        qv[nt][2] = r2 * r2; qv[nt][3] = r3 * r3;
    }

    #pragma unroll
    for (int d = 1; d <= 8; d <<= 1)
        #pragma unroll
        for (int nt = 0; nt < 4; ++nt)
            #pragma unroll
            for (int r = 0; r < 4; ++r) {
                sv[nt][r] += __shfl_xor(sv[nt][r], d);
                qv[nt][r] += __shfl_xor(qv[nt][r], d);
            }
    if (ml == 0) {
        #pragma unroll
        for (int nt = 0; nt < 4; ++nt)
            #pragma unroll
            for (int r = 0; r < 4; ++r) {
                int ch = nt * 16 + 4 * g + r;
                wstats[w][ch]      = sv[nt][r];
                wstats[w][64 + ch] = qv[nt][r];
            }
    }
    __syncthreads();
    if (t < 128) {
        float a = wstats[0][t] + wstats[1][t] + wstats[2][t] + wstats[3][t];
        outParts[(size_t)t * PSTR_ + blockIdx.x] = a;
    }
}

// ---------------------------------------------------------------------------
// QKV with HEAD-MAJOR outputs (R15; npb now compile-time template).
//   Q,K -> [b][h][pos][4]; V -> [b][h][dh][key]. Q pre-scaled by 0.5*log2e.
// ---------------------------------------------------------------------------
template<int NPB>
__global__ __launch_bounds__(256) void qkv_kernel(
    const float* __restrict__ tmpA,
    const _Float16* __restrict__ wqh, const float* __restrict__ bq,
    const _Float16* __restrict__ wkh, const float* __restrict__ bk,
    const _Float16* __restrict__ wvh, const float* __restrict__ bv,
    _Float16* __restrict__ qh, _Float16* __restrict__ kh, _Float16* __restrict__ vh,
    const float* __restrict__ partsIn,
    const float* __restrict__ gg, const float* __restrict__ bb)
{
    __shared__ half4_ Alds[64][17];
    __shared__ half4_ Wlds[64][17];
    __shared__ float  raw[128];
    __shared__ float  bnsc[64], bnsh[64];
    const int t    = threadIdx.x;
    const int m0   = blockIdx.x * 64;
    const int mode = blockIdx.y;           // 0=Q 1=K 2=V

    const _Float16* W = (mode == 0) ? wqh : (mode == 1) ? wkh : wvh;
    const float* bias = (mode == 0) ? bq  : (mode == 1) ? bk  : bv;
    const float  sc2  = (mode == 0) ? 0.5f * 1.44269504088896340736f : 1.f;

    if (t < 128) {
        const float* pr = partsIn + (size_t)t * PSTR_;
        float a = 0.f;
        #pragma unroll
        for (int j = 0; j < NPB; j += 4) {
            float4 v4 = *(const float4*)&pr[j];
            a += v4.x + v4.y + v4.z + v4.w;
        }
        raw[t] = a;
    }
    __syncthreads();
    if (t < 64) {
        float mean = raw[t] * INV_N_;
        float ex2  = raw[64 + t] * INV_N_;
        float rs   = rsqrtf(ex2 - mean * mean + EPS_);
        float s2   = gg[t] * rs;
        bnsc[t] = s2;
        bnsh[t] = bb[t] - mean * s2;
    }
    __syncthreads();

    #pragma unroll
    for (int i = 0; i < 4; ++i) {
        int l = i * 256 + t;
        int row = l >> 4, c4 = l & 15;
        float4 av = *(const float4*)&tmpA[(size_t)(m0 + row) * 64 + c4 * 4];
        int c = c4 * 4;
        av.x = fmaf(av.x, bnsc[c + 0], bnsh[c + 0]);
        av.y = fmaf(av.y, bnsc[c + 1], bnsh[c + 1]);
        av.z = fmaf(av.z, bnsc[c + 2], bnsh[c + 2]);
        av.w = fmaf(av.w, bnsc[c + 3], bnsh[c + 3]);
        Alds[row][c4] = half4_{(_Float16)av.x, (_Float16)av.y,
                               (_Float16)av.z, (_Float16)av.w};
        Wlds[row][c4] = *(const half4_*)&W[(size_t)row * 64 + c4 * 4];
    }
    __syncthreads();

    const int lane = t & 63, w = t >> 6, g = lane >> 4, ml = lane & 15;

    f32x4 acc[4] = {};
    #pragma unroll
    for (int kci = 0; kci < 4; ++kci) {
        half4_ af = Alds[w * 16 + ml][kci * 4 + g];
        #pragma unroll
        for (int nt = 0; nt < 4; ++nt) {
            half4_ wf = Wlds[nt * 16 + ml][kci * 4 + g];
            acc[nt] = __builtin_amdgcn_mfma_f32_16x16x16f16(wf, af, acc[nt], 0, 0, 0);
        }
    }

    const int m    = m0 + w * 16 + ml;
    const int bidx = m >> 10, row = m & 1023;
    #pragma unroll
    for (int nt = 0; nt < 4; ++nt) {
        const int nc = nt * 16 + 4 * g;
        const int h  = nc >> 2;
        float4 bv4 = *(const float4*)&bias[nc];
        float r0 = fmaxf(acc[nt][0] + bv4.x, 0.f) * sc2;
        float r1 = fmaxf(acc[nt][1] + bv4.y, 0.f) * sc2;
        float r2 = fmaxf(acc[nt][2] + bv4.z, 0.f) * sc2;
        float r3 = fmaxf(acc[nt][3] + bv4.w, 0.f) * sc2;
        if (mode == 2) {                   // V transposed: [b][h][dh][key]
            size_t base = ((size_t)(bidx * 16 + h) * 4) * 1024 + row;
            vh[base + 0]    = (_Float16)r0;
            vh[base + 1024] = (_Float16)r1;
            vh[base + 2048] = (_Float16)r2;
            vh[base + 3072] = (_Float16)r3;
        } else {                           // Q/K head-major: [b][h][pos][4]
            _Float16* Cq = (mode == 0) ? qh : kh;
            half4_ hs = { (_Float16)r0, (_Float16)r1, (_Float16)r2, (_Float16)r3 };
            *(half4_*)&Cq[((size_t)(bidx * 16 + h) * 1024 + row) * 4] = hs;
        }
    }
}

// ---------------------------------------------------------------------------
// Fused feed-forward: tmpA = relu(relu(BN(tmpB)@W1^T+b1)@W2^T+b2) + BN(tmpB),
// stats epilogue. 16 rows/block, grid 512 (2/CU), 4 waves.
// GEMM1: wave w -> h1 channels w*64..+63 -> LDS H (RNE casts). GEMM2: wave w
// -> out channels w*16..+15, K=256 from H. Stats written per-wave directly
// (disjoint channels), col = blockIdx.x (512 cols, PSTR_=512).
// ---------------------------------------------------------------------------
__global__ __launch_bounds__(256) void ffused_kernel(
    const float* __restrict__ tmpB, const _Float16* __restrict__ w1h,
    const float* __restrict__ b1, const _Float16* __restrict__ w2h,
    const float* __restrict__ b2, float* __restrict__ tmpA,
    const float* __restrict__ partsB,
    const float* __restrict__ gg, const float* __restrict__ bb,
    float* __restrict__ outParts)
{
    __shared__ half4_   Alds[16][17];
    __shared__ _Float16 H[16][264];
    __shared__ float    raw[128];
    __shared__ float    bnsc[64], bnsh[64];
    const int t  = threadIdx.x;
    const int m0 = blockIdx.x * 16;

    if (t < 128) {                         // partsB: 64 producer cols (attn)
        const float* pr = partsB + (size_t)t * PSTR_;
        float a = 0.f;
        #pragma unroll
        for (int j = 0; j < 64; j += 4) {
            float4 v4 = *(const float4*)&pr[j];
            a += v4.x + v4.y + v4.z + v4.w;
        }
        raw[t] = a;
    }
    __syncthreads();
    if (t < 64) {
        float mean = raw[t] * INV_N_;
        float ex2  = raw[64 + t] * INV_N_;
        float rs   = rsqrtf(ex2 - mean * mean + EPS_);
        float s2   = gg[t] * rs;
        bnsc[t] = s2;
        bnsh[t] = bb[t] - mean * s2;
    }
    __syncthreads();

    {                                      // A: 16 rows x 16 half4 (one pass)
        int row = t >> 4, c4 = t & 15;
        float4 av = *(const float4*)&tmpB[(size_t)(m0 + row) * 64 + c4 * 4];
        int c = c4 * 4;
        av.x = fmaf(av.x, bnsc[c + 0], bnsh[c + 0]);
        av.y = fmaf(av.y, bnsc[c + 1], bnsh[c + 1]);
        av.z = fmaf(av.z, bnsc[c + 2], bnsh[c + 2]);
        av.w = fmaf(av.w, bnsc[c + 3], bnsh[c + 3]);
        Alds[row][c4] = half4_{(_Float16)av.x, (_Float16)av.y,
                               (_Float16)av.z, (_Float16)av.w};
    }
    __syncthreads();

    const int lane = t & 63, w = t >> 6, g = lane >> 4, ml = lane & 15;

    // GEMM1: wave w -> h1 n-tiles w*4+ntl (W1 fragments direct from global)
    f32x4 acc1[4] = {};
    #pragma unroll
    for (int kci = 0; kci < 4; ++kci) {
        half4_ af = Alds[ml][kci * 4 + g];
        #pragma unroll
        for (int ntl = 0; ntl < 4; ++ntl) {
            int nt = w * 4 + ntl;
            half4_ wf = *(const half4_*)&w1h[(size_t)(nt * 16 + ml) * 64 + kci * 16 + 4 * g];
            acc1[ntl] = __builtin_amdgcn_mfma_f32_16x16x16f16(wf, af, acc1[ntl], 0, 0, 0);
        }
    }
    // bias + relu + RNE cvt -> H
    #pragma unroll
    for (int ntl = 0; ntl < 4; ++ntl) {
        int nt = w * 4 + ntl;
        float4 b1v = *(const float4*)&b1[nt * 16 + 4 * g];
        half4_ hv = { (_Float16)fmaxf(acc1[ntl][0] + b1v.x, 0.f),
                      (_Float16)fmaxf(acc1[ntl][1] + b1v.y, 0.f),
                      (_Float16)fmaxf(acc1[ntl][2] + b1v.z, 0.f),
                      (_Float16)fmaxf(acc1[ntl][3] + b1v.w, 0.f) };
        *(half4_*)&H[ml][nt * 16 + 4 * g] = hv;
    }
    __syncthreads();

    // GEMM2: wave w -> output channels w*16..+15, K = 256 from H
    f32x4 acc2 = {};
    #pragma unroll
    for (int kci2 = 0; kci2 < 16; ++kci2) {
        half4_ af2 = *(const half4_*)&H[ml][kci2 * 16 + 4 * g];
        half4_ wf2 = *(const half4_*)&w2h[(size_t)(w * 16 + ml) * 256 + kci2 * 16 + 4 * g];
        acc2 = __builtin_amdgcn_mfma_f32_16x16x16f16(wf2, af2, acc2, 0, 0, 0);
    }

    // epilogue: bias, relu, + BN'd residual (Alds), store, per-wave stats
    const int m  = m0 + ml;
    const int nc = w * 16 + 4 * g;
    float4 b2v = *(const float4*)&b2[nc];
    half4_ rr  = Alds[ml][w * 4 + g];
    float r0 = fmaxf(acc2[0] + b2v.x, 0.f) + (float)rr[0];
    float r1 = fmaxf(acc2[1] + b2v.y, 0.f) + (float)rr[1];
    float r2 = fmaxf(acc2[2] + b2v.z, 0.f) + (float)rr[2];
    float r3 = fmaxf(acc2[3] + b2v.w, 0.f) + (float)rr[3];
    float4 o4 = { r0, r1, r2, r3 };
    *(float4*)&tmpA[(size_t)m * 64 + nc] = o4;

    float sv[4] = { r0, r1, r2, r3 };
    float qv[4] = { r0 * r0, r1 * r1, r2 * r2, r3 * r3 };
    #pragma unroll
    for (int d = 1; d <= 8; d <<= 1)
        #pragma unroll
        for (int r = 0; r < 4; ++r) {
            sv[r] += __shfl_xor(sv[r], d);
            qv[r] += __shfl_xor(qv[r], d);
        }
    if (ml == 0) {
        #pragma unroll
        for (int r = 0; r < 4; ++r) {
            outParts[(size_t)(nc + r) * PSTR_ + blockIdx.x]      = sv[r];
            outParts[(size_t)(64 + nc + r) * PSTR_ + blockIdx.x] = qv[r];
        }
    }
}

// ---------------------------------------------------------------------------
// MFMA attention, head-major inputs (R13/R15, npb templated).
// ---------------------------------------------------------------------------
template<int NPB>
__global__ __launch_bounds__(256) void attn_kernel(
    const _Float16* __restrict__ q, const _Float16* __restrict__ k,
    const _Float16* __restrict__ v, const float* __restrict__ encRaw,
    float* __restrict__ out, const float* __restrict__ partsIn,
    const float* __restrict__ gPrev, const float* __restrict__ bPrev,
    float* __restrict__ partsOut)
{
    __shared__ uint2 klds[1024];           // K[key][0..3] (8B per key)
    __shared__ uint2 vlds[1024];           // [c*16 + g*4 + d] = {V[c*16+4g+j][d]}
    __shared__ float raw8[8], rsc[4], rsh[4];
    __shared__ float wred[4][8];

    const int bid = blockIdx.x;            // ((b*16 + h)*8 + qc)
    const int qc  = bid & 7;
    const int h   = (bid >> 3) & 15;
    const int b   = bid >> 7;
    const int t   = threadIdx.x;

    if (t < 8) {
        const int row = (t >> 2) * 64 + 4 * h + (t & 3);
        const float* pr = partsIn + (size_t)row * PSTR_;
        float a = 0.f;
        #pragma unroll
        for (int j = 0; j < NPB; j += 4) {
            float4 v4 = *(const float4*)&pr[j];
            a += v4.x + v4.y + v4.z + v4.w;
        }
        raw8[t] = a;
    }
    if (t < 4) {
        float mean = raw8[t] * INV_N_;
        float ex2  = raw8[4 + t] * INV_N_;
        float rs   = rsqrtf(ex2 - mean * mean + EPS_);
        float s2   = gPrev[4 * h + t] * rs;
        rsc[t] = s2;
        rsh[t] = bPrev[4 * h + t] - mean * s2;
    }

    const size_t baseqk = (size_t)(b * 16 + h) * 4096;   // halfs

    #pragma unroll
    for (int i = 0; i < 4; ++i) {
        int key = i * 256 + t;
        klds[key] = *(const uint2*)&k[baseqk + (size_t)key * 4];
        int e = (t >> 2) * 16 + (t & 3) * 4 + i;         // (c=t>>2, g=t&3, d=i)
        vlds[e] = *(const uint2*)&v[baseqk + (size_t)i * 1024 + t * 4];
    }
    __syncthreads();

    const int lane = t & 63;
    const int wv2  = t >> 6;
    const int ln16 = lane & 15;
    const int g16  = lane >> 4;
    const int q0   = qc * 128 + wv2 * 32;

    half4_ qf0 = { 0, 0, 0, 0 }, qf1 = { 0, 0, 0, 0 };
    if (lane < 16) {
        qf0 = __builtin_bit_cast(half4_,
              *(const uint2*)&q[baseqk + (size_t)(q0 + ln16) * 4]);
        qf1 = __builtin_bit_cast(half4_,
              *(const uint2*)&q[baseqk + (size_t)(q0 + 16 + ln16) * 4]);
    }

    const half4_ ones = { (_Float16)1.f, (_Float16)1.f, (_Float16)1.f, (_Float16)1.f };
    const f32x4  fz   = { 0.f, 0.f, 0.f, 0.f };
    f32x4 o0 = fz, o1 = fz;

    #pragma unroll 4
    for (int c = 0; c < 64; ++c) {
        half4_ ka = __builtin_bit_cast(half4_, klds[c * 16 + ln16]);
        half4_ va = __builtin_bit_cast(half4_, vlds[c * 16 + g16 * 4 + (ln16 & 3)]);
        if (ln16 == 4) va = ones;

        f32x4 s0 = __builtin_amdgcn_mfma_f32_16x16x16f16(ka, qf0, fz, 0, 0, 0);
        f32x4 s1 = __builtin_amdgcn_mfma_f32_16x16x16f16(ka, qf1, fz, 0, 0, 0);

        float e00 = __builtin_amdgcn_exp2f(s0[0]);
        float e01 = __builtin_amdgcn_exp2f(s0[1]);
        float e02 = __builtin_amdgcn_exp2f(s0[2]);
        float e03 = __builtin_amdgcn_exp2f(s0[3]);
        float e10 = __builtin_amdgcn_exp2f(s1[0]);
        float e11 = __builtin_amdgcn_exp2f(s1[1]);
        float e12 = __builtin_amdgcn_exp2f(s1[2]);
        float e13 = __builtin_amdgcn_exp2f(s1[3]);

        fp16x2 a0 = __builtin_amdgcn_cvt_pkrtz(e00, e01);
        fp16x2 b0 = __builtin_amdgcn_cvt_pkrtz(e02, e03);
        fp16x2 a1 = __builtin_amdgcn_cvt_pkrtz(e10, e11);
        fp16x2 b1 = __builtin_amdgcn_cvt_pkrtz(e12, e13);
        half4_ p0 = __builtin_bit_cast(half4_, __builtin_shufflevector(a0, b0, 0, 1, 2, 3));
        half4_ p1 = __builtin_bit_cast(half4_, __builtin_shufflevector(a1, b1, 0, 1, 2, 3));

        o0 = __builtin_amdgcn_mfma_f32_16x16x16f16(va, p0, o0, 0, 0, 0);
        o1 = __builtin_amdgcn_mfma_f32_16x16x16f16(va, p1, o1, 0, 0, 0);
    }

    float ls0 = __shfl(o0[0], 16 + ln16);
    float ls1 = __shfl(o1[0], 16 + ln16);

    float4 r0v = { 0.f, 0.f, 0.f, 0.f }, r1v = r0v;
    if (lane < 16) {
        {
            const size_t gi = (size_t)(b * L_ + q0 + ln16) * D_ + h * DH_;
            const float inv = 1.0f / ls0;
            const float4 e4 = *(const float4*)&encRaw[gi];
            r0v.x = fmaf(o0[0], inv, fmaf(e4.x, rsc[0], rsh[0]));
            r0v.y = fmaf(o0[1], inv, fmaf(e4.y, rsc[1], rsh[1]));
            r0v.z = fmaf(o0[2], inv, fmaf(e4.z, rsc[2], rsh[2]));
            r0v.w = fmaf(o0[3], inv, fmaf(e4.w, rsc[3], rsh[3]));
            *(float4*)&out[gi] = r0v;
        }
        {
            const size_t gi = (size_t)(b * L_ + q0 + 16 + ln16) * D_ + h * DH_;
            const float inv = 1.0f / ls1;
            const float4 e4 = *(const float4*)&encRaw[gi];
            r1v.x = fmaf(o1[0], inv, fmaf(e4.x, rsc[0], rsh[0]));
            r1v.y = fmaf(o1[1], inv, fmaf(e4.y, rsc[1], rsh[1]));
            r1v.z = fmaf(o1[2], inv, fmaf(e4.z, rsc[2], rsh[2]));
            r1v.w = fmaf(o1[3], inv, fmaf(e4.w, rsc[3], rsh[3]));
            *(float4*)&out[gi] = r1v;
        }
    }

    float s4[4] = { r0v.x + r1v.x, r0v.y + r1v.y, r0v.z + r1v.z, r0v.w + r1v.w };
    float q4[4] = { r0v.x*r0v.x + r1v.x*r1v.x, r0v.y*r0v.y + r1v.y*r1v.y,
                    r0v.z*r0v.z + r1v.z*r1v.z, r0v.w*r0v.w + r1v.w*r1v.w };
    #pragma unroll
    for (int d2 = 1; d2 <= 8; d2 <<= 1) {
        #pragma unroll
        for (int j = 0; j < 4; ++j) {
            s4[j] += __shfl_xor(s4[j], d2);
            q4[j] += __shfl_xor(q4[j], d2);
        }
    }
    if (lane == 0) {
        #pragma unroll
        for (int j = 0; j < 4; ++j) { wred[wv2][j] = s4[j]; wred[wv2][4 + j] = q4[j]; }
    }
    __syncthreads();
    if (t < 8) {
        float a = wred[0][t] + wred[1][t] + wred[2][t] + wred[3][t];
        const int row = (t >> 2) * 64 + 4 * h + (t & 3);
        partsOut[(size_t)row * PSTR_ + (b * 8 + qc)] = a;
    }
}

// ---------------------------------------------------------------------------
// Final BatchNorm apply (512 producer cols from ffused).
// ---------------------------------------------------------------------------
__global__ __launch_bounds__(256) void bn_apply_kernel(
    const float* __restrict__ x, const float* __restrict__ parts,
    const float* __restrict__ gamma, const float* __restrict__ beta,
    float* __restrict__ y)
{
    __shared__ float fstats[128];
    const int t = threadIdx.x;
    if (t < 128) {
        const float* pr = parts + (size_t)t * PSTR_;
        float a = 0.f;
        #pragma unroll
        for (int j = 0; j < 512; j += 4) {
            float4 v4 = *(const float4*)&pr[j];
            a += v4.x + v4.y + v4.z + v4.w;
        }
        fstats[t] = a;
    }
    __syncthreads();

    const int idx = blockIdx.x * 256 + t;
    const int c = (idx & 15) << 2;
    float4 xv = ((const float4*)x)[idx];
    float4 sm = *(const float4*)&fstats[c];
    float4 sq = *(const float4*)&fstats[64 + c];
    float4 g  = *(const float4*)&gamma[c];
    float4 be = *(const float4*)&beta[c];

    float mean[4] = {sm.x * INV_N_, sm.y * INV_N_, sm.z * INV_N_, sm.w * INV_N_};
    float ex2[4]  = {sq.x * INV_N_, sq.y * INV_N_, sq.z * INV_N_, sq.w * INV_N_};
    float xa[4] = {xv.x, xv.y, xv.z, xv.w};
    float ga[4] = {g.x, g.y, g.z, g.w};
    float ba[4] = {be.x, be.y, be.z, be.w};
    float ya[4];
    #pragma unroll
    for (int i = 0; i < 4; ++i) {
        float var = ex2[i] - mean[i] * mean[i];
        float rs = rsqrtf(var + EPS_);
        ya[i] = ga[i] * (xa[i] - mean[i]) * rs + ba[i];
    }
    float4 r = {ya[0], ya[1], ya[2], ya[3]};
    ((float4*)y)[idx] = r;
}

// ---------------------------------------------------------------------------
extern "C" void kernel_launch(void* const* d_in, const int* in_sizes, int n_in,
                              void* d_out, int out_size, void* d_ws, size_t ws_size,
                              hipStream_t stream)
{
    const float* x       = (const float*)d_in[0];
    const float* W_embed = (const float*)d_in[1];
    const float* b_embed = (const float*)d_in[2];
    const float* g0      = (const float*)d_in[3];
    const float* be0     = (const float*)d_in[4];
    const float* Wq      = (const float*)d_in[5];
    const float* bq      = (const float*)d_in[6];
    const float* Wk      = (const float*)d_in[7];
    const float* bk      = (const float*)d_in[8];
    const float* Wv      = (const float*)d_in[9];
    const float* bv      = (const float*)d_in[10];
    const float* g_attn  = (const float*)d_in[11];
    const float* be_attn = (const float*)d_in[12];
    const float* W1      = (const float*)d_in[13];
    const float* b1      = (const float*)d_in[14];
    const float* W2      = (const float*)d_in[15];
    const float* b2      = (const float*)d_in[16];
    const float* g_ff    = (const float*)d_in[17];
    const float* be_ff   = (const float*)d_in[18];

    float* ws     = (float*)d_ws;
    float* tmpA   = ws;                    // 524288 f32 (embed / ff out, pre-BN)
    float* tmpB   = ws + 524288;           // 524288 f32 (attn out, pre-BN)
    float* partsA = ws + 1048576;          // 65536 f32 (128 x 512)
    float* partsB = ws + 1114112;          // 65536 f32
    _Float16* hb  = (_Float16*)(ws + 1179648);
    _Float16* qh  = hb;                    // 524288 f16, head-major, x(0.5*log2e)
    _Float16* kh  = hb + 524288;           // head-major
    _Float16* vh  = hb + 1048576;          // head-major TRANSPOSED [b][h][dh][key]
    _Float16* wqh = hb + 1572864;          // converted weights, contiguous 45056
    _Float16* wkh = wqh + 4096;
    _Float16* wvh = wkh + 4096;
    _Float16* w1h = wvh + 4096;
    _Float16* w2h = w1h + 16384;
    float* out = (float*)d_out;

    const dim3 blk(256);

    embed_kernel<<<128, blk, 0, stream>>>(
        x, W_embed, Wq, Wk, Wv, W1, W2, b_embed, tmpA, partsA, wqh);

    for (int s = 0; s < 3; ++s) {
        const float* gP  = (s == 0) ? g0  : g_ff;
        const float* beP = (s == 0) ? be0 : be_ff;
        if (s == 0) {
            qkv_kernel<128><<<dim3(128, 3), blk, 0, stream>>>(
                tmpA, wqh, bq, wkh, bk, wvh, bv, qh, kh, vh, partsA, gP, beP);
            attn_kernel<128><<<1024, blk, 0, stream>>>(
                qh, kh, vh, tmpA, tmpB, partsA, gP, beP, partsB);
        } else {
            qkv_kernel<512><<<dim3(128, 3), blk, 0, stream>>>(
                tmpA, wqh, bq, wkh, bk, wvh, bv, qh, kh, vh, partsA, gP, beP);
            attn_kernel<512><<<1024, blk, 0, stream>>>(
                qh, kh, vh, tmpA, tmpB, partsA, gP, beP, partsB);
        }
        ffused_kernel<<<512, blk, 0, stream>>>(
            tmpB, w1h, b1, w2h, b2, tmpA, partsB, g_attn, be_attn, partsA);
    }
    bn_apply_kernel<<<512, blk, 0, stream>>>(tmpA, partsA, g_ff, be_ff, out);
}

// Round 18
// 172.373 us; speedup vs baseline: 1.1163x; 1.1163x over previous
//
#include <hip/hip_runtime.h>
#include <hip/hip_cooperative_groups.h>
#include <math.h>

namespace cg = cooperative_groups;

// Problem constants
static constexpr int B_ = 8, L_ = 1024, D_ = 64, H_ = 16, DH_ = 4, DFF_ = 256;
static constexpr int M_ = B_ * L_;
static constexpr float EPS_ = 1e-5f;
static constexpr float INV_N_ = 1.0f / (float)M_;
static constexpr int PSTR_ = 256;            // parts row stride (max producer cols)
static constexpr unsigned SMEM_ = 32768;     // mega dynamic LDS (2 blocks/CU at 64KB)

typedef _Float16 half4_ __attribute__((ext_vector_type(4)));
typedef __fp16   fp16x2 __attribute__((ext_vector_type(2)));
typedef float    f32x4  __attribute__((ext_vector_type(4)));

struct MParams {
    const float *x, *W_embed, *b_embed, *g0, *be0;
    const float *Wq, *bq, *Wk, *bk, *Wv, *bv, *g_attn, *be_attn;
    const float *W1, *b1, *W2, *b2, *g_ff, *be_ff;
    float *tmpA, *tmpB, *partsA, *partsB;
    _Float16 *qh, *kh, *vh, *h1, *wqh, *wkh, *wvh, *w1h, *w2h;
    float *out;
};

// ---------------------------------------------------------------------------
// embed (blk 0..127): tmpA = x @ W_embed^T + b (W cvt inline), stats ->
// partsA cols 0..127. C^T MFMA convention. LDS 19456 B.
// ---------------------------------------------------------------------------
__device__ __forceinline__ void embed_work(char* sm, int blk, const MParams& p)
{
    half4_* Alds  = (half4_*)sm;            // 64*17
    half4_* Wlds  = (half4_*)(sm + 8704);
    float*  wstat = (float*)(sm + 17408);   // 4*128
    const int t  = threadIdx.x;
    const int m0 = blk * 64;

    #pragma unroll
    for (int i = 0; i < 4; ++i) {
        int l = i * 256 + t;
        int row = l >> 4, c4 = l & 15;
        float4 av = *(const float4*)&p.x[(size_t)(m0 + row) * 64 + c4 * 4];
        Alds[row * 17 + c4] = half4_{(_Float16)av.x, (_Float16)av.y,
                                     (_Float16)av.z, (_Float16)av.w};
        float4 wv4 = *(const float4*)&p.W_embed[(size_t)row * 64 + c4 * 4];
        Wlds[row * 17 + c4] = half4_{(_Float16)wv4.x, (_Float16)wv4.y,
                                     (_Float16)wv4.z, (_Float16)wv4.w};
    }
    __syncthreads();

    const int lane = t & 63, w = t >> 6, g = lane >> 4, ml = lane & 15;

    f32x4 acc[4] = {};
    #pragma unroll
    for (int kci = 0; kci < 4; ++kci) {
        half4_ af = Alds[(w * 16 + ml) * 17 + kci * 4 + g];
        #pragma unroll
        for (int nt = 0; nt < 4; ++nt) {
            half4_ wf = Wlds[(nt * 16 + ml) * 17 + kci * 4 + g];
            acc[nt] = __builtin_amdgcn_mfma_f32_16x16x16f16(wf, af, acc[nt], 0, 0, 0);
        }
    }

    const int m = m0 + w * 16 + ml;
    float sv[4][4], qv[4][4];
    #pragma unroll
    for (int nt = 0; nt < 4; ++nt) {
        const int nc = nt * 16 + 4 * g;
        float4 bv4 = *(const float4*)&p.b_embed[nc];
        float r0 = acc[nt][0] + bv4.x, r1 = acc[nt][1] + bv4.y;
        float r2 = acc[nt][2] + bv4.z, r3 = acc[nt][3] + bv4.w;
        float4 o4 = { r0, r1, r2, r3 };
        *(float4*)&p.tmpA[(size_t)m * 64 + nc] = o4;
        sv[nt][0] = r0; sv[nt][1] = r1; sv[nt][2] = r2; sv[nt][3] = r3;
        qv[nt][0] = r0 * r0; qv[nt][1] = r1 * r1;
        qv[nt][2] = r2 * r2; qv[nt][3] = r3 * r3;
    }

    #pragma unroll
    for (int d = 1; d <= 8; d <<= 1)
        #pragma unroll
        for (int nt = 0; nt < 4; ++nt)
            #pragma unroll
            for (int r = 0; r < 4; ++r) {
                sv[nt][r] += __shfl_xor(sv[nt][r], d);
                qv[nt][r] += __shfl_xor(qv[nt][r], d);
            }
    if (ml == 0) {
        #pragma unroll
        for (int nt = 0; nt < 4; ++nt)
            #pragma unroll
            for (int r = 0; r < 4; ++r) {
                int ch = nt * 16 + 4 * g + r;
                wstat[w * 128 + ch]      = sv[nt][r];
                wstat[w * 128 + 64 + ch] = qv[nt][r];
            }
    }
    __syncthreads();
    if (t < 128) {
        float a = wstat[t] + wstat[128 + t] + wstat[256 + t] + wstat[384 + t];
        p.partsA[(size_t)t * PSTR_ + blk] = a;
    }
}

// weight cvt (blk 128..303): wq|wk|wv|w1|w2 -> f16 (contiguous at wqh).
__device__ __forceinline__ void wcvt_work(int blk, int t, const MParams& p)
{
    int e = (blk - 128) * 256 + t;          // 0..45055
    if (e < 45056) {
        float v;
        if      (e <  4096) v = p.Wq[e];
        else if (e <  8192) v = p.Wk[e - 4096];
        else if (e < 12288) v = p.Wv[e - 8192];
        else if (e < 28672) v = p.W1[e - 12288];
        else                v = p.W2[e - 28672];
        p.wqh[e] = (_Float16)v;
    }
}

// ---------------------------------------------------------------------------
// qkv (blk 0..383): mode = blk>>7, m0 = (blk&127)*64. Head-major outputs;
// Q pre-scaled by 0.5*log2e. LDS 18432 B.
// ---------------------------------------------------------------------------
template<int NPB>
__device__ __forceinline__ void qkv_work(char* sm, int blk, const MParams& p,
                                         const float* gg, const float* bb)
{
    half4_* Alds = (half4_*)sm;
    half4_* Wlds = (half4_*)(sm + 8704);
    float*  raw  = (float*)(sm + 17408);    // 128
    float*  bnsc = (float*)(sm + 17920);    // 64
    float*  bnsh = (float*)(sm + 18176);    // 64
    const int t    = threadIdx.x;
    const int m0   = (blk & 127) * 64;
    const int mode = blk >> 7;

    const _Float16* W = (mode == 0) ? p.wqh : (mode == 1) ? p.wkh : p.wvh;
    const float* bias = (mode == 0) ? p.bq  : (mode == 1) ? p.bk  : p.bv;
    const float  sc2  = (mode == 0) ? 0.5f * 1.44269504088896340736f : 1.f;

    if (t < 128) {
        const float* pr = p.partsA + (size_t)t * PSTR_;
        float a = 0.f;
        #pragma unroll
        for (int j = 0; j < NPB; j += 4) {
            float4 v4 = *(const float4*)&pr[j];
            a += v4.x + v4.y + v4.z + v4.w;
        }
        raw[t] = a;
    }
    __syncthreads();
    if (t < 64) {
        float mean = raw[t] * INV_N_;
        float ex2  = raw[64 + t] * INV_N_;
        float rs   = rsqrtf(ex2 - mean * mean + EPS_);
        float s2   = gg[t] * rs;
        bnsc[t] = s2;
        bnsh[t] = bb[t] - mean * s2;
    }
    __syncthreads();

    #pragma unroll
    for (int i = 0; i < 4; ++i) {
        int l = i * 256 + t;
        int row = l >> 4, c4 = l & 15;
        float4 av = *(const float4*)&p.tmpA[(size_t)(m0 + row) * 64 + c4 * 4];
        int c = c4 * 4;
        av.x = fmaf(av.x, bnsc[c + 0], bnsh[c + 0]);
        av.y = fmaf(av.y, bnsc[c + 1], bnsh[c + 1]);
        av.z = fmaf(av.z, bnsc[c + 2], bnsh[c + 2]);
        av.w = fmaf(av.w, bnsc[c + 3], bnsh[c + 3]);
        Alds[row * 17 + c4] = half4_{(_Float16)av.x, (_Float16)av.y,
                                     (_Float16)av.z, (_Float16)av.w};
        Wlds[row * 17 + c4] = *(const half4_*)&W[(size_t)row * 64 + c4 * 4];
    }
    __syncthreads();

    const int lane = t & 63, w = t >> 6, g = lane >> 4, ml = lane & 15;

    f32x4 acc[4] = {};
    #pragma unroll
    for (int kci = 0; kci < 4; ++kci) {
        half4_ af = Alds[(w * 16 + ml) * 17 + kci * 4 + g];
        #pragma unroll
        for (int nt = 0; nt < 4; ++nt) {
            half4_ wf = Wlds[(nt * 16 + ml) * 17 + kci * 4 + g];
            acc[nt] = __builtin_amdgcn_mfma_f32_16x16x16f16(wf, af, acc[nt], 0, 0, 0);
        }
    }

    const int m    = m0 + w * 16 + ml;
    const int bidx = m >> 10, row = m & 1023;
    #pragma unroll
    for (int nt = 0; nt < 4; ++nt) {
        const int nc = nt * 16 + 4 * g;
        const int h  = nc >> 2;
        float4 bv4 = *(const float4*)&bias[nc];
        float r0 = fmaxf(acc[nt][0] + bv4.x, 0.f) * sc2;
        float r1 = fmaxf(acc[nt][1] + bv4.y, 0.f) * sc2;
        float r2 = fmaxf(acc[nt][2] + bv4.z, 0.f) * sc2;
        float r3 = fmaxf(acc[nt][3] + bv4.w, 0.f) * sc2;
        if (mode == 2) {                    // V transposed: [b][h][dh][key]
            size_t base = ((size_t)(bidx * 16 + h) * 4) * 1024 + row;
            p.vh[base + 0]    = (_Float16)r0;
            p.vh[base + 1024] = (_Float16)r1;
            p.vh[base + 2048] = (_Float16)r2;
            p.vh[base + 3072] = (_Float16)r3;
        } else {                            // Q/K head-major: [b][h][pos][4]
            _Float16* Cq = (mode == 0) ? p.qh : p.kh;
            half4_ hs = { (_Float16)r0, (_Float16)r1, (_Float16)r2, (_Float16)r3 };
            *(half4_*)&Cq[((size_t)(bidx * 16 + h) * 1024 + row) * 4] = hs;
        }
    }
}

// ---------------------------------------------------------------------------
// attention (unit 0..1023), head-major inputs (R15 structure). LDS 16576 B.
// ---------------------------------------------------------------------------
template<int NPB>
__device__ __forceinline__ void attn_work(char* sm, int unit, const MParams& p,
                                          const float* gPrev, const float* bPrev)
{
    uint2* klds = (uint2*)sm;               // 1024
    uint2* vlds = (uint2*)(sm + 8192);      // 1024
    float* raw8 = (float*)(sm + 16384);
    float* rsc  = (float*)(sm + 16416);
    float* rsh  = (float*)(sm + 16432);
    float* wred = (float*)(sm + 16448);     // 4*8

    const int qc = unit & 7;
    const int h  = (unit >> 3) & 15;
    const int b  = unit >> 7;
    const int t  = threadIdx.x;

    if (t < 8) {
        const int row = (t >> 2) * 64 + 4 * h + (t & 3);
        const float* pr = p.partsA + (size_t)row * PSTR_;
        float a = 0.f;
        #pragma unroll
        for (int j = 0; j < NPB; j += 4) {
            float4 v4 = *(const float4*)&pr[j];
            a += v4.x + v4.y + v4.z + v4.w;
        }
        raw8[t] = a;
    }
    if (t < 4) {
        float mean = raw8[t] * INV_N_;
        float ex2  = raw8[4 + t] * INV_N_;
        float rs   = rsqrtf(ex2 - mean * mean + EPS_);
        float s2   = gPrev[4 * h + t] * rs;
        rsc[t] = s2;
        rsh[t] = bPrev[4 * h + t] - mean * s2;
    }

    const size_t baseqk = (size_t)(b * 16 + h) * 4096;   // halfs

    #pragma unroll
    for (int i = 0; i < 4; ++i) {
        int key = i * 256 + t;
        klds[key] = *(const uint2*)&p.kh[baseqk + (size_t)key * 4];
        int e = (t >> 2) * 16 + (t & 3) * 4 + i;
        vlds[e] = *(const uint2*)&p.vh[baseqk + (size_t)i * 1024 + t * 4];
    }
    __syncthreads();

    const int lane = t & 63;
    const int wv2  = t >> 6;
    const int ln16 = lane & 15;
    const int g16  = lane >> 4;
    const int q0   = qc * 128 + wv2 * 32;

    half4_ qf0 = { 0, 0, 0, 0 }, qf1 = { 0, 0, 0, 0 };
    if (lane < 16) {
        qf0 = __builtin_bit_cast(half4_,
              *(const uint2*)&p.qh[baseqk + (size_t)(q0 + ln16) * 4]);
        qf1 = __builtin_bit_cast(half4_,
              *(const uint2*)&p.qh[baseqk + (size_t)(q0 + 16 + ln16) * 4]);
    }

    const half4_ ones = { (_Float16)1.f, (_Float16)1.f, (_Float16)1.f, (_Float16)1.f };
    const f32x4  fz   = { 0.f, 0.f, 0.f, 0.f };
    f32x4 o0 = fz, o1 = fz;

    #pragma unroll 4
    for (int c = 0; c < 64; ++c) {
        half4_ ka = __builtin_bit_cast(half4_, klds[c * 16 + ln16]);
        half4_ va = __builtin_bit_cast(half4_, vlds[c * 16 + g16 * 4 + (ln16 & 3)]);
        if (ln16 == 4) va = ones;

        f32x4 s0 = __builtin_amdgcn_mfma_f32_16x16x16f16(ka, qf0, fz, 0, 0, 0);
        f32x4 s1 = __builtin_amdgcn_mfma_f32_16x16x16f16(ka, qf1, fz, 0, 0, 0);

        float e00 = __builtin_amdgcn_exp2f(s0[0]);
        float e01 = __builtin_amdgcn_exp2f(s0[1]);
        float e02 = __builtin_amdgcn_exp2f(s0[2]);
        float e03 = __builtin_amdgcn_exp2f(s0[3]);
        float e10 = __builtin_amdgcn_exp2f(s1[0]);
        float e11 = __builtin_amdgcn_exp2f(s1[1]);
        float e12 = __builtin_amdgcn_exp2f(s1[2]);
        float e13 = __builtin_amdgcn_exp2f(s1[3]);

        fp16x2 a0 = __builtin_amdgcn_cvt_pkrtz(e00, e01);
        fp16x2 b0 = __builtin_amdgcn_cvt_pkrtz(e02, e03);
        fp16x2 a1 = __builtin_amdgcn_cvt_pkrtz(e10, e11);
        fp16x2 b1 = __builtin_amdgcn_cvt_pkrtz(e12, e13);
        half4_ p0 = __builtin_bit_cast(half4_, __builtin_shufflevector(a0, b0, 0, 1, 2, 3));
        half4_ p1 = __builtin_bit_cast(half4_, __builtin_shufflevector(a1, b1, 0, 1, 2, 3));

        o0 = __builtin_amdgcn_mfma_f32_16x16x16f16(va, p0, o0, 0, 0, 0);
        o1 = __builtin_amdgcn_mfma_f32_16x16x16f16(va, p1, o1, 0, 0, 0);
    }

    float ls0 = __shfl(o0[0], 16 + ln16);
    float ls1 = __shfl(o1[0], 16 + ln16);

    float4 r0v = { 0.f, 0.f, 0.f, 0.f }, r1v = r0v;
    if (lane < 16) {
        {
            const size_t gi = (size_t)(b * L_ + q0 + ln16) * D_ + h * DH_;
            const float inv = 1.0f / ls0;
            const float4 e4 = *(const float4*)&p.tmpA[gi];
            r0v.x = fmaf(o0[0], inv, fmaf(e4.x, rsc[0], rsh[0]));
            r0v.y = fmaf(o0[1], inv, fmaf(e4.y, rsc[1], rsh[1]));
            r0v.z = fmaf(o0[2], inv, fmaf(e4.z, rsc[2], rsh[2]));
            r0v.w = fmaf(o0[3], inv, fmaf(e4.w, rsc[3], rsh[3]));
            *(float4*)&p.tmpB[gi] = r0v;
        }
        {
            const size_t gi = (size_t)(b * L_ + q0 + 16 + ln16) * D_ + h * DH_;
            const float inv = 1.0f / ls1;
            const float4 e4 = *(const float4*)&p.tmpA[gi];
            r1v.x = fmaf(o1[0], inv, fmaf(e4.x, rsc[0], rsh[0]));
            r1v.y = fmaf(o1[1], inv, fmaf(e4.y, rsc[1], rsh[1]));
            r1v.z = fmaf(o1[2], inv, fmaf(e4.z, rsc[2], rsh[2]));
            r1v.w = fmaf(o1[3], inv, fmaf(e4.w, rsc[3], rsh[3]));
            *(float4*)&p.tmpB[gi] = r1v;
        }
    }

    float s4[4] = { r0v.x + r1v.x, r0v.y + r1v.y, r0v.z + r1v.z, r0v.w + r1v.w };
    float q4[4] = { r0v.x*r0v.x + r1v.x*r1v.x, r0v.y*r0v.y + r1v.y*r1v.y,
                    r0v.z*r0v.z + r1v.z*r1v.z, r0v.w*r0v.w + r1v.w*r1v.w };
    #pragma unroll
    for (int d2 = 1; d2 <= 8; d2 <<= 1) {
        #pragma unroll
        for (int j = 0; j < 4; ++j) {
            s4[j] += __shfl_xor(s4[j], d2);
            q4[j] += __shfl_xor(q4[j], d2);
        }
    }
    if (lane == 0) {
        #pragma unroll
        for (int j = 0; j < 4; ++j) { wred[wv2 * 8 + j] = s4[j]; wred[wv2 * 8 + 4 + j] = q4[j]; }
    }
    __syncthreads();
    if (t < 8) {
        float a = wred[t] + wred[8 + t] + wred[16 + t] + wred[24 + t];
        const int row = (t >> 2) * 64 + 4 * h + (t & 3);
        p.partsB[(size_t)row * PSTR_ + (b * 8 + qc)] = a;
    }
}

// ---------------------------------------------------------------------------
// ff1 (blk 0..511): h1 = relu(BN(tmpB) @ W1^T + b1) f16. LDS 18432 B.
// ---------------------------------------------------------------------------
__device__ __forceinline__ void ff1_work(char* sm, int blk, const MParams& p)
{
    half4_* Alds = (half4_*)sm;
    half4_* Wlds = (half4_*)(sm + 8704);
    float*  raw  = (float*)(sm + 17408);
    float*  bnsc = (float*)(sm + 17920);
    float*  bnsh = (float*)(sm + 18176);
    const int t  = threadIdx.x;
    const int m0 = (blk & 127) * 64;
    const int n0 = (blk >> 7) * 64;

    if (t < 128) {
        const float* pr = p.partsB + (size_t)t * PSTR_;
        float a = 0.f;
        #pragma unroll
        for (int j = 0; j < 64; j += 4) {
            float4 v4 = *(const float4*)&pr[j];
            a += v4.x + v4.y + v4.z + v4.w;
        }
        raw[t] = a;
    }
    __syncthreads();
    if (t < 64) {
        float mean = raw[t] * INV_N_;
        float ex2  = raw[64 + t] * INV_N_;
        float rs   = rsqrtf(ex2 - mean * mean + EPS_);
        float s2   = p.g_attn[t] * rs;
        bnsc[t] = s2;
        bnsh[t] = p.be_attn[t] - mean * s2;
    }
    __syncthreads();

    #pragma unroll
    for (int i = 0; i < 4; ++i) {
        int l = i * 256 + t;
        int row = l >> 4, c4 = l & 15;
        float4 av = *(const float4*)&p.tmpB[(size_t)(m0 + row) * 64 + c4 * 4];
        int c = c4 * 4;
        av.x = fmaf(av.x, bnsc[c + 0], bnsh[c + 0]);
        av.y = fmaf(av.y, bnsc[c + 1], bnsh[c + 1]);
        av.z = fmaf(av.z, bnsc[c + 2], bnsh[c + 2]);
        av.w = fmaf(av.w, bnsc[c + 3], bnsh[c + 3]);
        Alds[row * 17 + c4] = half4_{(_Float16)av.x, (_Float16)av.y,
                                     (_Float16)av.z, (_Float16)av.w};
        Wlds[row * 17 + c4] = *(const half4_*)&p.w1h[(size_t)(n0 + row) * 64 + c4 * 4];
    }
    __syncthreads();

    const int lane = t & 63, w = t >> 6, g = lane >> 4, ml = lane & 15;

    f32x4 acc[4] = {};
    #pragma unroll
    for (int kci = 0; kci < 4; ++kci) {
        half4_ af = Alds[(w * 16 + ml) * 17 + kci * 4 + g];
        #pragma unroll
        for (int nt = 0; nt < 4; ++nt) {
            half4_ wf = Wlds[(nt * 16 + ml) * 17 + kci * 4 + g];
            acc[nt] = __builtin_amdgcn_mfma_f32_16x16x16f16(wf, af, acc[nt], 0, 0, 0);
        }
    }

    const int m = m0 + w * 16 + ml;
    #pragma unroll
    for (int nt = 0; nt < 4; ++nt) {
        const int nc = n0 + nt * 16 + 4 * g;
        float4 bv4 = *(const float4*)&p.b1[nc];
        half4_ hs = { (_Float16)fmaxf(acc[nt][0] + bv4.x, 0.f),
                      (_Float16)fmaxf(acc[nt][1] + bv4.y, 0.f),
                      (_Float16)fmaxf(acc[nt][2] + bv4.z, 0.f),
                      (_Float16)fmaxf(acc[nt][3] + bv4.w, 0.f) };
        *(half4_*)&p.h1[(size_t)m * 256 + nc] = hs;
    }
}

// ---------------------------------------------------------------------------
// ff2 (blk 0..511): 32-row x 32-ch tile; mb = blk&255, nh = blk>>8.
// tmpA = relu(h1 @ W2^T + b2) + BN(tmpB); stats -> partsA col mb, rows of
// this nh only (disjoint). BN coefs per-thread in REGISTERS (LDS reused);
// A/W tiles stride-64 cells with XOR bank swizzle. LDS 32768 B exactly.
// ---------------------------------------------------------------------------
__device__ __forceinline__ void ff2_work(char* sm, int blk, const MParams& p)
{
    const int t  = threadIdx.x;
    const int mb = blk & 255;
    const int nh = blk >> 8;
    const int m0 = mb * 32;
    const int lane = t & 63, w = t >> 6, g = lane >> 4, ml = lane & 15;
    const int mhalf = w & 1, ntile = w >> 1;
    const int ch = nh * 32 + ntile * 16 + 4 * g;   // this thread's 4 channels

    // phase a: reduce partsB into LDS scratch (reused for tiles after)
    float* scratch = (float*)sm;            // 128 floats
    if (t < 128) {
        const float* pr = p.partsB + (size_t)t * PSTR_;
        float a = 0.f;
        #pragma unroll
        for (int j = 0; j < 64; j += 4) {
            float4 v4 = *(const float4*)&pr[j];
            a += v4.x + v4.y + v4.z + v4.w;
        }
        scratch[t] = a;
    }
    __syncthreads();
    // phase b: per-thread BN coefs (registers)
    float scR[4], shR[4];
    #pragma unroll
    for (int i = 0; i < 4; ++i) {
        float mean = scratch[ch + i] * INV_N_;
        float ex2  = scratch[64 + ch + i] * INV_N_;
        float rs   = rsqrtf(ex2 - mean * mean + EPS_);
        float s2   = p.g_attn[ch + i] * rs;
        scR[i] = s2;
        shR[i] = p.be_attn[ch + i] - mean * s2;
    }
    __syncthreads();

    // phase c: stage tiles (overwrites scratch); XOR swizzle c4 ^= row&7
    half4_* Alds = (half4_*)sm;             // 32 rows * 64 cells
    half4_* Wlds = (half4_*)(sm + 16384);
    #pragma unroll
    for (int i = 0; i < 8; ++i) {
        int l = i * 256 + t;
        int row = l >> 6, c4 = l & 63;
        int sw = c4 ^ (row & 7);
        Alds[row * 64 + sw] = *(const half4_*)&p.h1[(size_t)(m0 + row) * 256 + c4 * 4];
        Wlds[row * 64 + sw] = *(const half4_*)&p.w2h[(size_t)(nh * 32 + row) * 256 + c4 * 4];
    }
    __syncthreads();

    f32x4 acc = {};
    const int arow = mhalf * 16 + ml, wrow = ntile * 16 + ml;
    #pragma unroll
    for (int kci = 0; kci < 16; ++kci) {
        half4_ af = Alds[arow * 64 + ((kci * 4 + g) ^ (arow & 7))];
        half4_ wf = Wlds[wrow * 64 + ((kci * 4 + g) ^ (wrow & 7))];
        acc = __builtin_amdgcn_mfma_f32_16x16x16f16(wf, af, acc, 0, 0, 0);
    }

    const int m = m0 + mhalf * 16 + ml;
    float4 b2v = *(const float4*)&p.b2[ch];
    float r0 = fmaxf(acc[0] + b2v.x, 0.f);
    float r1 = fmaxf(acc[1] + b2v.y, 0.f);
    float r2 = fmaxf(acc[2] + b2v.z, 0.f);
    float r3 = fmaxf(acc[3] + b2v.w, 0.f);
    float4 rv = *(const float4*)&p.tmpB[(size_t)m * 64 + ch];
    r0 += fmaf(rv.x, scR[0], shR[0]);
    r1 += fmaf(rv.y, scR[1], shR[1]);
    r2 += fmaf(rv.z, scR[2], shR[2]);
    r3 += fmaf(rv.w, scR[3], shR[3]);
    float4 o4 = { r0, r1, r2, r3 };
    *(float4*)&p.tmpA[(size_t)m * 64 + ch] = o4;

    float sv[4] = { r0, r1, r2, r3 };
    float qv[4] = { r0 * r0, r1 * r1, r2 * r2, r3 * r3 };
    #pragma unroll
    for (int d = 1; d <= 8; d <<= 1)
        #pragma unroll
        for (int r = 0; r < 4; ++r) {
            sv[r] += __shfl_xor(sv[r], d);
            qv[r] += __shfl_xor(qv[r], d);
        }
    __syncthreads();                        // all tile reads done; reuse LDS
    float* wstat = (float*)sm;              // 4 waves * 32 floats
    if (ml == 0) {
        #pragma unroll
        for (int r = 0; r < 4; ++r) {
            wstat[w * 32 + 4 * g + r]      = sv[r];
            wstat[w * 32 + 16 + 4 * g + r] = qv[r];
        }
    }
    __syncthreads();
    if (t < 64) {
        const int nt2 = t >> 5, j = t & 31;
        float a = wstat[(nt2 * 2 + 0) * 32 + j] + wstat[(nt2 * 2 + 1) * 32 + j];
        const int chL = j & 15, isSq = j >> 4;
        const int row = isSq * 64 + nh * 32 + nt2 * 16 + chL;
        p.partsA[(size_t)row * PSTR_ + mb] = a;
    }
}

// ---------------------------------------------------------------------------
// Final BN apply (blk 0..511), 256 producer cols.
// ---------------------------------------------------------------------------
__device__ __forceinline__ void bn_work(char* sm, int blk, const MParams& p)
{
    float* fstats = (float*)sm;
    const int t = threadIdx.x;
    if (t < 128) {
        const float* pr = p.partsA + (size_t)t * PSTR_;
        float a = 0.f;
        #pragma unroll
        for (int j = 0; j < 256; j += 4) {
            float4 v4 = *(const float4*)&pr[j];
            a += v4.x + v4.y + v4.z + v4.w;
        }
        fstats[t] = a;
    }
    __syncthreads();

    const int idx = blk * 256 + t;
    const int c = (idx & 15) << 2;
    float4 xv = ((const float4*)p.tmpA)[idx];
    float4 sm4 = *(const float4*)&fstats[c];
    float4 sq  = *(const float4*)&fstats[64 + c];
    float4 g4  = *(const float4*)&p.g_ff[c];
    float4 be4 = *(const float4*)&p.be_ff[c];

    float mean[4] = {sm4.x * INV_N_, sm4.y * INV_N_, sm4.z * INV_N_, sm4.w * INV_N_};
    float ex2[4]  = {sq.x * INV_N_, sq.y * INV_N_, sq.z * INV_N_, sq.w * INV_N_};
    float xa[4] = {xv.x, xv.y, xv.z, xv.w};
    float ga[4] = {g4.x, g4.y, g4.z, g4.w};
    float ba[4] = {be4.x, be4.y, be4.z, be4.w};
    float ya[4];
    #pragma unroll
    for (int i = 0; i < 4; ++i) {
        float var = ex2[i] - mean[i] * mean[i];
        float rs = rsqrtf(var + EPS_);
        ya[i] = ga[i] * (xa[i] - mean[i]) * rs + ba[i];
    }
    float4 r = {ya[0], ya[1], ya[2], ya[3]};
    ((float4*)p.out)[idx] = r;
}

// ---------------------------------------------------------------------------
// Cooperative megakernel: 512 blocks x 256 threads, 2 blocks/CU.
// attn covers 1024 units via 2 reps/block.
// ---------------------------------------------------------------------------
__global__ void __launch_bounds__(256, 2) mega_kernel(MParams p)
{
    extern __shared__ char sm[];
    cg::grid_group grid = cg::this_grid();
    const int blk = blockIdx.x;
    const int t   = threadIdx.x;

    if (blk < 128)      embed_work(sm, blk, p);
    else if (blk < 304) wcvt_work(blk, t, p);
    grid.sync();

    #pragma unroll 1
    for (int s = 0; s < 3; ++s) {
        const float* gP  = (s == 0) ? p.g0  : p.g_ff;
        const float* beP = (s == 0) ? p.be0 : p.be_ff;
        if (blk < 384) {
            if (s == 0) qkv_work<128>(sm, blk, p, gP, beP);
            else        qkv_work<256>(sm, blk, p, gP, beP);
        }
        grid.sync();
        if (s == 0) { attn_work<128>(sm, blk, p, gP, beP);
                      attn_work<128>(sm, blk + 512, p, gP, beP); }
        else        { attn_work<256>(sm, blk, p, gP, beP);
                      attn_work<256>(sm, blk + 512, p, gP, beP); }
        grid.sync();
        ff1_work(sm, blk, p);
        grid.sync();
        ff2_work(sm, blk, p);
        grid.sync();
    }
    bn_work(sm, blk, p);
}

// ---------------------------------------------------------------------------
// Fallback wrappers (ordinary launches of the same bodies).
// ---------------------------------------------------------------------------
__global__ void __launch_bounds__(256) fb_phase0(MParams p)
{
    extern __shared__ char sm[];
    if (blockIdx.x < 128) embed_work(sm, blockIdx.x, p);
    else                  wcvt_work(blockIdx.x, threadIdx.x, p);
}
template<int NPB>
__global__ void __launch_bounds__(256) fb_qkv(MParams p, const float* gg, const float* bb)
{
    extern __shared__ char sm[];
    qkv_work<NPB>(sm, blockIdx.x, p, gg, bb);
}
template<int NPB>
__global__ void __launch_bounds__(256) fb_attn(MParams p, const float* gg, const float* bb)
{
    extern __shared__ char sm[];
    attn_work<NPB>(sm, blockIdx.x, p, gg, bb);
}
__global__ void __launch_bounds__(256) fb_ff1(MParams p)
{
    extern __shared__ char sm[];
    ff1_work(sm, blockIdx.x, p);
}
__global__ void __launch_bounds__(256) fb_ff2(MParams p)
{
    extern __shared__ char sm[];
    ff2_work(sm, blockIdx.x, p);
}
__global__ void __launch_bounds__(256) fb_bn(MParams p)
{
    extern __shared__ char sm[];
    bn_work(sm, blockIdx.x, p);
}

// ---------------------------------------------------------------------------
extern "C" void kernel_launch(void* const* d_in, const int* in_sizes, int n_in,
                              void* d_out, int out_size, void* d_ws, size_t ws_size,
                              hipStream_t stream)
{
    MParams p;
    p.x       = (const float*)d_in[0];
    p.W_embed = (const float*)d_in[1];
    p.b_embed = (const float*)d_in[2];
    p.g0      = (const float*)d_in[3];
    p.be0     = (const float*)d_in[4];
    p.Wq      = (const float*)d_in[5];
    p.bq      = (const float*)d_in[6];
    p.Wk      = (const float*)d_in[7];
    p.bk      = (const float*)d_in[8];
    p.Wv      = (const float*)d_in[9];
    p.bv      = (const float*)d_in[10];
    p.g_attn  = (const float*)d_in[11];
    p.be_attn = (const float*)d_in[12];
    p.W1      = (const float*)d_in[13];
    p.b1      = (const float*)d_in[14];
    p.W2      = (const float*)d_in[15];
    p.b2      = (const float*)d_in[16];
    p.g_ff    = (const float*)d_in[17];
    p.be_ff   = (const float*)d_in[18];

    float* ws = (float*)d_ws;
    p.tmpA   = ws;                          // 524288 f32
    p.tmpB   = ws + 524288;                 // 524288 f32
    p.partsA = ws + 1048576;                // 32768 f32 (128 x 256)
    p.partsB = ws + 1081344;                // 32768 f32
    _Float16* hb = (_Float16*)(ws + 1114112);
    p.qh  = hb;                             // head-major, x(0.5*log2e)
    p.kh  = hb + 524288;
    p.vh  = hb + 1048576;                   // [b][h][dh][key]
    p.h1  = hb + 1572864;
    p.wqh = hb + 3670016;                   // contiguous converted weights
    p.wkh = p.wqh + 4096;
    p.wvh = p.wkh + 4096;
    p.w1h = p.wvh + 4096;
    p.w2h = p.w1h + 16384;
    p.out = (float*)d_out;

    // Guarded cooperative launch: pure occupancy query first (capture-safe).
    int nb = 0;
    hipError_t qerr = hipOccupancyMaxActiveBlocksPerMultiprocessor(
        &nb, (const void*)mega_kernel, 256, SMEM_);
    bool done = false;
    if (qerr == hipSuccess && nb >= 2) {
        void* args[] = { &p };
        hipError_t e = hipLaunchCooperativeKernel(
            (const void*)mega_kernel, dim3(512), dim3(256), args, SMEM_, stream);
        done = (e == hipSuccess);
    }
    if (done) return;

    // Fallback: same bodies as ordinary dispatches (R15-equivalent).
    const dim3 blk(256);
    fb_phase0<<<304, blk, 19456, stream>>>(p);
    for (int s = 0; s < 3; ++s) {
        const float* gP  = (s == 0) ? p.g0  : p.g_ff;
        const float* beP = (s == 0) ? p.be0 : p.be_ff;
        if (s == 0) {
            fb_qkv<128><<<384, blk, 18432, stream>>>(p, gP, beP);
            fb_attn<128><<<1024, blk, 16576, stream>>>(p, gP, beP);
        } else {
            fb_qkv<256><<<384, blk, 18432, stream>>>(p, gP, beP);
            fb_attn<256><<<1024, blk, 16576, stream>>>(p, gP, beP);
        }
        fb_ff1<<<512, blk, 18432, stream>>>(p);
        fb_ff2<<<512, blk, 32768, stream>>>(p);
    }
    fb_bn<<<512, blk, 512, stream>>>(p);
}

// Round 19
// 155.235 us; speedup vs baseline: 1.2395x; 1.1104x over previous
//
#include <hip/hip_runtime.h>
#include <math.h>

// Problem constants
static constexpr int B_ = 8, L_ = 1024, D_ = 64, H_ = 16, DH_ = 4, DFF_ = 256;
static constexpr int M_ = B_ * L_;          // 8192 rows
static constexpr float EPS_ = 1e-5f;
static constexpr float INV_N_ = 1.0f / (float)M_;   // BN normalizer
static constexpr int PSTR_ = 128;           // parts row stride (cols = producer blocks)

typedef _Float16 half4_ __attribute__((ext_vector_type(4)));
typedef __fp16   fp16x2 __attribute__((ext_vector_type(2)));  // cvt_pkrtz return type
typedef float    f32x4  __attribute__((ext_vector_type(4)));

// ---------------------------------------------------------------------------
// Weight prep: convert all weights to f16 into one contiguous ws region.
// ---------------------------------------------------------------------------
__global__ __launch_bounds__(256) void prep_kernel(
    const float* __restrict__ we, const float* __restrict__ wq,
    const float* __restrict__ wk, const float* __restrict__ wv,
    const float* __restrict__ w1, const float* __restrict__ w2,
    _Float16* __restrict__ dst)
{
    int e = blockIdx.x * 256 + threadIdx.x;
    float v;
    if      (e <  4096) v = we[e];
    else if (e <  8192) v = wq[e - 4096];
    else if (e < 12288) v = wk[e - 8192];
    else if (e < 16384) v = wv[e - 12288];
    else if (e < 32768) v = w1[e - 16384];
    else                v = w2[e - 32768];
    dst[e] = (_Float16)v;
}

// ---------------------------------------------------------------------------
// MFMA linear (embed / ff1): C^T convention.
// acc[nt] reg r at lane (g,ml) = C[m0+w*16+ml][n0+nt*16+4g+r].
// ---------------------------------------------------------------------------
template<int KT, int AF16, int BN_A, int RELU, int RESID_BN, int STATS, int OUTF16>
__device__ __forceinline__ void linear_mfma(
    const float* __restrict__ Af, const _Float16* __restrict__ Ah,
    const _Float16* __restrict__ Wh,
    const float* __restrict__ bias, const float* __restrict__ resid,
    float* __restrict__ Cf, _Float16* __restrict__ Ch, float outScale,
    int N, int m0, int n0,
    const float* __restrict__ partsIn, int npb,
    const float* __restrict__ gg, const float* __restrict__ bb,
    float* __restrict__ outParts, int blkIdx)
{
    constexpr int CPR = KT / 4;            // half4 cells per row
    __shared__ half4_ Alds[64][CPR + 1];
    __shared__ half4_ Wlds[64][CPR + 1];
    __shared__ float  raw[128];
    __shared__ float  bnsc[64], bnsh[64];
    __shared__ float  wstats[4][128];
    const int t = threadIdx.x;

    if (BN_A || RESID_BN) {
        if (t < 128) {
            const float* pr = partsIn + (size_t)t * PSTR_;
            float a = 0.f;
            for (int j = 0; j < npb; j += 4) {
                float4 v4 = *(const float4*)&pr[j];
                a += v4.x + v4.y + v4.z + v4.w;
            }
            raw[t] = a;
        }
        __syncthreads();
        if (t < 64) {
            float mean = raw[t] * INV_N_;
            float ex2  = raw[64 + t] * INV_N_;
            float rs   = rsqrtf(ex2 - mean * mean + EPS_);
            float s2   = gg[t] * rs;
            bnsc[t] = s2;
            bnsh[t] = bb[t] - mean * s2;
        }
        __syncthreads();
    }

    {
        constexpr int ITERS = (64 * CPR) / 256;
        #pragma unroll
        for (int i = 0; i < ITERS; ++i) {
            int l = i * 256 + t;
            int row = l / CPR, c4 = l % CPR;
            half4_ hv;
            if (AF16) {
                hv = *(const half4_*)&Ah[(size_t)(m0 + row) * KT + c4 * 4];
            } else {
                float4 av = *(const float4*)&Af[(size_t)(m0 + row) * KT + c4 * 4];
                if (BN_A) {
                    int c = c4 * 4;
                    av.x = fmaf(av.x, bnsc[c + 0], bnsh[c + 0]);
                    av.y = fmaf(av.y, bnsc[c + 1], bnsh[c + 1]);
                    av.z = fmaf(av.z, bnsc[c + 2], bnsh[c + 2]);
                    av.w = fmaf(av.w, bnsc[c + 3], bnsh[c + 3]);
                }
                hv = half4_{(_Float16)av.x, (_Float16)av.y,
                            (_Float16)av.z, (_Float16)av.w};
            }
            Alds[row][c4] = hv;
            Wlds[row][c4] = *(const half4_*)&Wh[(size_t)(n0 + row) * KT + c4 * 4];
        }
    }
    __syncthreads();

    const int lane = t & 63, w = t >> 6, g = lane >> 4, ml = lane & 15;

    f32x4 acc[4] = {};
    #pragma unroll
    for (int kci = 0; kci < KT / 16; ++kci) {
        half4_ af = Alds[w * 16 + ml][kci * 4 + g];
        #pragma unroll
        for (int nt = 0; nt < 4; ++nt) {
            half4_ wf = Wlds[nt * 16 + ml][kci * 4 + g];
            acc[nt] = __builtin_amdgcn_mfma_f32_16x16x16f16(wf, af, acc[nt], 0, 0, 0);
        }
    }

    const int m = m0 + w * 16 + ml;
    float sv[4][4], qv[4][4];
    #pragma unroll
    for (int nt = 0; nt < 4; ++nt) {
        const int cb = nt * 16 + 4 * g;
        const int nc = n0 + cb;
        float4 bv4 = *(const float4*)&bias[nc];
        float r0 = acc[nt][0] + bv4.x, r1 = acc[nt][1] + bv4.y;
        float r2 = acc[nt][2] + bv4.z, r3 = acc[nt][3] + bv4.w;
        if (RELU) {
            r0 = fmaxf(r0, 0.f); r1 = fmaxf(r1, 0.f);
            r2 = fmaxf(r2, 0.f); r3 = fmaxf(r3, 0.f);
        }
        if (RESID_BN) {
            float4 rv = *(const float4*)&resid[(size_t)m * N + nc];
            r0 += fmaf(rv.x, bnsc[cb + 0], bnsh[cb + 0]);
            r1 += fmaf(rv.y, bnsc[cb + 1], bnsh[cb + 1]);
            r2 += fmaf(rv.z, bnsc[cb + 2], bnsh[cb + 2]);
            r3 += fmaf(rv.w, bnsc[cb + 3], bnsh[cb + 3]);
        }
        if (OUTF16) {
            half4_ hs = { (_Float16)(r0 * outScale), (_Float16)(r1 * outScale),
                          (_Float16)(r2 * outScale), (_Float16)(r3 * outScale) };
            *(half4_*)&Ch[(size_t)m * N + nc] = hs;
        } else {
            float4 o4 = { r0, r1, r2, r3 };
            *(float4*)&Cf[(size_t)m * N + nc] = o4;
        }
        if (STATS) {
            sv[nt][0] = r0; sv[nt][1] = r1; sv[nt][2] = r2; sv[nt][3] = r3;
            qv[nt][0] = r0 * r0; qv[nt][1] = r1 * r1;
            qv[nt][2] = r2 * r2; qv[nt][3] = r3 * r3;
        }
    }

    if (STATS) {
        #pragma unroll
        for (int d = 1; d <= 8; d <<= 1)
            #pragma unroll
            for (int nt = 0; nt < 4; ++nt)
                #pragma unroll
                for (int r = 0; r < 4; ++r) {
                    sv[nt][r] += __shfl_xor(sv[nt][r], d);
                    qv[nt][r] += __shfl_xor(qv[nt][r], d);
                }
        if (ml == 0) {
            #pragma unroll
            for (int nt = 0; nt < 4; ++nt)
                #pragma unroll
                for (int r = 0; r < 4; ++r) {
                    int ch = nt * 16 + 4 * g + r;
                    wstats[w][ch]      = sv[nt][r];
                    wstats[w][64 + ch] = qv[nt][r];
                }
        }
        __syncthreads();
        if (t < 128) {
            float a = wstats[0][t] + wstats[1][t] + wstats[2][t] + wstats[3][t];
            outParts[(size_t)t * PSTR_ + blkIdx] = a;
        }
    }
}

__global__ __launch_bounds__(256) void embed_kernel(
    const float* __restrict__ x, const _Float16* __restrict__ wemh,
    const float* __restrict__ bias, float* __restrict__ C,
    float* __restrict__ outParts)
{
    linear_mfma<64, 0, 0, 0, 0, 1, 0>(x, nullptr, wemh, bias, nullptr,
                                      C, nullptr, 1.f, 64, blockIdx.x * 64, 0,
                                      nullptr, 0, nullptr, nullptr,
                                      outParts, blockIdx.x);
}

// ---------------------------------------------------------------------------
// QKV with HEAD-MAJOR outputs:
//   Q,K -> [b][h][pos][4]      (lane's half4 = one head's 4 dims: coalesced)
//   V   -> [b][h][dh][key]     (transposed per head: 4 scalar stores/lane)
// Q pre-scaled by 0.5*log2e (bare v_exp in attn).
// ---------------------------------------------------------------------------
__global__ __launch_bounds__(256) void qkv_kernel(
    const float* __restrict__ tmpA,
    const _Float16* __restrict__ wqh, const float* __restrict__ bq,
    const _Float16* __restrict__ wkh, const float* __restrict__ bk,
    const _Float16* __restrict__ wvh, const float* __restrict__ bv,
    _Float16* __restrict__ qh, _Float16* __restrict__ kh, _Float16* __restrict__ vh,
    const float* __restrict__ partsIn,
    const float* __restrict__ gg, const float* __restrict__ bb)
{
    __shared__ half4_ Alds[64][17];
    __shared__ half4_ Wlds[64][17];
    __shared__ float  raw[128];
    __shared__ float  bnsc[64], bnsh[64];
    const int t    = threadIdx.x;
    const int m0   = blockIdx.x * 64;
    const int mode = blockIdx.y;           // 0=Q 1=K 2=V

    const _Float16* W = (mode == 0) ? wqh : (mode == 1) ? wkh : wvh;
    const float* bias = (mode == 0) ? bq  : (mode == 1) ? bk  : bv;
    const float  sc2  = (mode == 0) ? 0.5f * 1.44269504088896340736f : 1.f;

    if (t < 128) {
        const float* pr = partsIn + (size_t)t * PSTR_;
        float a = 0.f;
        for (int j = 0; j < 128; j += 4) {
            float4 v4 = *(const float4*)&pr[j];
            a += v4.x + v4.y + v4.z + v4.w;
        }
        raw[t] = a;
    }
    __syncthreads();
    if (t < 64) {
        float mean = raw[t] * INV_N_;
        float ex2  = raw[64 + t] * INV_N_;
        float rs   = rsqrtf(ex2 - mean * mean + EPS_);
        float s2   = gg[t] * rs;
        bnsc[t] = s2;
        bnsh[t] = bb[t] - mean * s2;
    }
    __syncthreads();

    #pragma unroll
    for (int i = 0; i < 4; ++i) {
        int l = i * 256 + t;
        int row = l >> 4, c4 = l & 15;
        float4 av = *(const float4*)&tmpA[(size_t)(m0 + row) * 64 + c4 * 4];
        int c = c4 * 4;
        av.x = fmaf(av.x, bnsc[c + 0], bnsh[c + 0]);
        av.y = fmaf(av.y, bnsc[c + 1], bnsh[c + 1]);
        av.z = fmaf(av.z, bnsc[c + 2], bnsh[c + 2]);
        av.w = fmaf(av.w, bnsc[c + 3], bnsh[c + 3]);
        Alds[row][c4] = half4_{(_Float16)av.x, (_Float16)av.y,
                               (_Float16)av.z, (_Float16)av.w};
        Wlds[row][c4] = *(const half4_*)&W[(size_t)row * 64 + c4 * 4];
    }
    __syncthreads();

    const int lane = t & 63, w = t >> 6, g = lane >> 4, ml = lane & 15;

    f32x4 acc[4] = {};
    #pragma unroll
    for (int kci = 0; kci < 4; ++kci) {
        half4_ af = Alds[w * 16 + ml][kci * 4 + g];
        #pragma unroll
        for (int nt = 0; nt < 4; ++nt) {
            half4_ wf = Wlds[nt * 16 + ml][kci * 4 + g];
            acc[nt] = __builtin_amdgcn_mfma_f32_16x16x16f16(wf, af, acc[nt], 0, 0, 0);
        }
    }

    const int m    = m0 + w * 16 + ml;
    const int bidx = m >> 10, row = m & 1023;
    #pragma unroll
    for (int nt = 0; nt < 4; ++nt) {
        const int nc = nt * 16 + 4 * g;
        const int h  = nc >> 2;            // 4g,nc multiples of 4 -> one head
        float4 bv4 = *(const float4*)&bias[nc];
        float r0 = fmaxf(acc[nt][0] + bv4.x, 0.f) * sc2;
        float r1 = fmaxf(acc[nt][1] + bv4.y, 0.f) * sc2;
        float r2 = fmaxf(acc[nt][2] + bv4.z, 0.f) * sc2;
        float r3 = fmaxf(acc[nt][3] + bv4.w, 0.f) * sc2;
        if (mode == 2) {                   // V transposed: [b][h][dh][key]
            size_t base = ((size_t)(bidx * 16 + h) * 4) * 1024 + row;
            vh[base + 0]    = (_Float16)r0;
            vh[base + 1024] = (_Float16)r1;
            vh[base + 2048] = (_Float16)r2;
            vh[base + 3072] = (_Float16)r3;
        } else {                           // Q/K head-major: [b][h][pos][4]
            _Float16* C = (mode == 0) ? qh : kh;
            half4_ hs = { (_Float16)r0, (_Float16)r1, (_Float16)r2, (_Float16)r3 };
            *(half4_*)&C[((size_t)(bidx * 16 + h) * 1024 + row) * 4] = hs;
        }
    }
}

__global__ __launch_bounds__(256) void ff1_kernel(
    const float* __restrict__ tmpB, const _Float16* __restrict__ w1h,
    const float* __restrict__ b1, _Float16* __restrict__ h1,
    const float* __restrict__ partsB,
    const float* __restrict__ g, const float* __restrict__ be)
{
    linear_mfma<64, 0, 1, 1, 0, 0, 1>(tmpB, nullptr, w1h, b1, nullptr,
                                      nullptr, h1, 1.f, 256,
                                      blockIdx.x * 64, blockIdx.y * 64,
                                      partsB, 64, g, be, nullptr, 0);
}

// ---------------------------------------------------------------------------
// ff2: grid (128, 2). x = 64-row m-block, y = 32-channel n-half -> 256
// blocks. Each block: h1-tile + its half of W2 in LDS; stats write DISJOINT
// rows of column x (no race).
// ---------------------------------------------------------------------------
__global__ __launch_bounds__(256) void ff2_kernel(
    const _Float16* __restrict__ h1, const _Float16* __restrict__ w2h,
    const float* __restrict__ b2, const float* __restrict__ tmpB,
    float* __restrict__ tmpA, const float* __restrict__ partsB,
    const float* __restrict__ gg, const float* __restrict__ bb,
    float* __restrict__ outParts)
{
    __shared__ half4_ Alds[64][65];        // h1: 64 rows x 256 (f16)
    __shared__ half4_ Wlds[32][65];        // W2 rows nh*32..+31 x 256
    __shared__ float  raw[128];
    __shared__ float  bnsc[64], bnsh[64];
    __shared__ float  wstats[4][64];
    const int t  = threadIdx.x;
    const int m0 = blockIdx.x * 64;
    const int nh = blockIdx.y;             // channels nh*32 .. nh*32+31

    if (t < 128) {
        const float* pr = partsB + (size_t)t * PSTR_;
        float a = 0.f;
        for (int j = 0; j < 64; j += 4) {
            float4 v4 = *(const float4*)&pr[j];
            a += v4.x + v4.y + v4.z + v4.w;
        }
        raw[t] = a;
    }
    __syncthreads();
    if (t < 64) {
        float mean = raw[t] * INV_N_;
        float ex2  = raw[64 + t] * INV_N_;
        float rs   = rsqrtf(ex2 - mean * mean + EPS_);
        float s2   = gg[t] * rs;
        bnsc[t] = s2;
        bnsh[t] = bb[t] - mean * s2;
    }
    __syncthreads();

    #pragma unroll
    for (int i = 0; i < 16; ++i) {
        int l = i * 256 + t;
        int row = l >> 6, c4 = l & 63;
        Alds[row][c4] = *(const half4_*)&h1[(size_t)(m0 + row) * 256 + c4 * 4];
    }
    #pragma unroll
    for (int i = 0; i < 8; ++i) {
        int l = i * 256 + t;
        int row = l >> 6, c4 = l & 63;
        Wlds[row][c4] = *(const half4_*)&w2h[(size_t)(nh * 32 + row) * 256 + c4 * 4];
    }
    __syncthreads();

    const int lane = t & 63, w = t >> 6, g = lane >> 4, ml = lane & 15;

    f32x4 acc[2] = {};
    #pragma unroll
    for (int kci = 0; kci < 16; ++kci) {
        half4_ af = Alds[w * 16 + ml][kci * 4 + g];
        #pragma unroll
        for (int nt = 0; nt < 2; ++nt) {
            half4_ wf = Wlds[nt * 16 + ml][kci * 4 + g];
            acc[nt] = __builtin_amdgcn_mfma_f32_16x16x16f16(wf, af, acc[nt], 0, 0, 0);
        }
    }

    const int m = m0 + w * 16 + ml;
    float sv[2][4], qv[2][4];
    #pragma unroll
    for (int nt = 0; nt < 2; ++nt) {
        const int c2 = nt * 16 + 4 * g;    // 0..31 within the half
        const int ch = nh * 32 + c2;       // global channel
        float4 b2v = *(const float4*)&b2[ch];
        float r0 = fmaxf(acc[nt][0] + b2v.x, 0.f);
        float r1 = fmaxf(acc[nt][1] + b2v.y, 0.f);
        float r2 = fmaxf(acc[nt][2] + b2v.z, 0.f);
        float r3 = fmaxf(acc[nt][3] + b2v.w, 0.f);
        float4 rv = *(const float4*)&tmpB[(size_t)m * 64 + ch];
        r0 += fmaf(rv.x, bnsc[ch + 0], bnsh[ch + 0]);
        r1 += fmaf(rv.y, bnsc[ch + 1], bnsh[ch + 1]);
        r2 += fmaf(rv.z, bnsc[ch + 2], bnsh[ch + 2]);
        r3 += fmaf(rv.w, bnsc[ch + 3], bnsh[ch + 3]);
        float4 o4 = { r0, r1, r2, r3 };
        *(float4*)&tmpA[(size_t)m * 64 + ch] = o4;
        sv[nt][0] = r0; sv[nt][1] = r1; sv[nt][2] = r2; sv[nt][3] = r3;
        qv[nt][0] = r0 * r0; qv[nt][1] = r1 * r1;
        qv[nt][2] = r2 * r2; qv[nt][3] = r3 * r3;
    }

    #pragma unroll
    for (int d = 1; d <= 8; d <<= 1)
        #pragma unroll
        for (int nt = 0; nt < 2; ++nt)
            #pragma unroll
            for (int r = 0; r < 4; ++r) {
                sv[nt][r] += __shfl_xor(sv[nt][r], d);
                qv[nt][r] += __shfl_xor(qv[nt][r], d);
            }
    if (ml == 0) {
        #pragma unroll
        for (int nt = 0; nt < 2; ++nt)
            #pragma unroll
            for (int r = 0; r < 4; ++r) {
                int c2 = nt * 16 + 4 * g + r;          // 0..31
                wstats[w][c2]      = sv[nt][r];
                wstats[w][32 + c2] = qv[nt][r];
            }
    }
    __syncthreads();
    if (t < 64) {                          // t<32: sums, t>=32: sumsqs
        float a = wstats[0][t] + wstats[1][t] + wstats[2][t] + wstats[3][t];
        const int row = (t >> 5) * 64 + nh * 32 + (t & 31);
        outParts[(size_t)row * PSTR_ + blockIdx.x] = a;
    }
}

// ---------------------------------------------------------------------------
// MFMA attention, head-major inputs (best known: R13/R15).
// ---------------------------------------------------------------------------
__global__ __launch_bounds__(256) void attn_kernel(
    const _Float16* __restrict__ q, const _Float16* __restrict__ k,
    const _Float16* __restrict__ v, const float* __restrict__ encRaw,
    float* __restrict__ out, const float* __restrict__ partsIn,
    const float* __restrict__ gPrev, const float* __restrict__ bPrev,
    float* __restrict__ partsOut)
{
    __shared__ uint2 klds[1024];           // K[key][0..3] (8B per key)
    __shared__ uint2 vlds[1024];           // [c*16 + g*4 + d] = {V[c*16+4g+j][d]}
    __shared__ float raw8[8], rsc[4], rsh[4];
    __shared__ float wred[4][8];

    const int bid = blockIdx.x;            // ((b*16 + h)*8 + qc)
    const int qc  = bid & 7;
    const int h   = (bid >> 3) & 15;
    const int b   = bid >> 7;
    const int t   = threadIdx.x;

    if (t < 8) {
        const int row = (t >> 2) * 64 + 4 * h + (t & 3);
        const float* pr = partsIn + (size_t)row * PSTR_;
        float a = 0.f;
        for (int j = 0; j < 128; j += 4) {
            float4 v4 = *(const float4*)&pr[j];
            a += v4.x + v4.y + v4.z + v4.w;
        }
        raw8[t] = a;
    }
    if (t < 4) {
        float mean = raw8[t] * INV_N_;
        float ex2  = raw8[4 + t] * INV_N_;
        float rs   = rsqrtf(ex2 - mean * mean + EPS_);
        float s2   = gPrev[4 * h + t] * rs;
        rsc[t] = s2;
        rsh[t] = bPrev[4 * h + t] - mean * s2;
    }

    const size_t baseqk = (size_t)(b * 16 + h) * 4096;   // halfs

    #pragma unroll
    for (int i = 0; i < 4; ++i) {
        int key = i * 256 + t;
        klds[key] = *(const uint2*)&k[baseqk + (size_t)key * 4];
        int e = (t >> 2) * 16 + (t & 3) * 4 + i;         // (c=t>>2, g=t&3, d=i)
        vlds[e] = *(const uint2*)&v[baseqk + (size_t)i * 1024 + t * 4];
    }
    __syncthreads();

    const int lane = t & 63;
    const int wv2  = t >> 6;
    const int ln16 = lane & 15;
    const int g16  = lane >> 4;
    const int q0   = qc * 128 + wv2 * 32;

    half4_ qf0 = { 0, 0, 0, 0 }, qf1 = { 0, 0, 0, 0 };
    if (lane < 16) {
        qf0 = __builtin_bit_cast(half4_,
              *(const uint2*)&q[baseqk + (size_t)(q0 + ln16) * 4]);
        qf1 = __builtin_bit_cast(half4_,
              *(const uint2*)&q[baseqk + (size_t)(q0 + 16 + ln16) * 4]);
    }

    const half4_ ones = { (_Float16)1.f, (_Float16)1.f, (_Float16)1.f, (_Float16)1.f };
    const f32x4  fz   = { 0.f, 0.f, 0.f, 0.f };
    f32x4 o0 = fz, o1 = fz;

    #pragma unroll 4
    for (int c = 0; c < 64; ++c) {
        half4_ ka = __builtin_bit_cast(half4_, klds[c * 16 + ln16]);
        half4_ va = __builtin_bit_cast(half4_, vlds[c * 16 + g16 * 4 + (ln16 & 3)]);
        if (ln16 == 4) va = ones;

        f32x4 s0 = __builtin_amdgcn_mfma_f32_16x16x16f16(ka, qf0, fz, 0, 0, 0);
        f32x4 s1 = __builtin_amdgcn_mfma_f32_16x16x16f16(ka, qf1, fz, 0, 0, 0);

        float e00 = __builtin_amdgcn_exp2f(s0[0]);
        float e01 = __builtin_amdgcn_exp2f(s0[1]);
        float e02 = __builtin_amdgcn_exp2f(s0[2]);
        float e03 = __builtin_amdgcn_exp2f(s0[3]);
        float e10 = __builtin_amdgcn_exp2f(s1[0]);
        float e11 = __builtin_amdgcn_exp2f(s1[1]);
        float e12 = __builtin_amdgcn_exp2f(s1[2]);
        float e13 = __builtin_amdgcn_exp2f(s1[3]);

        fp16x2 a0 = __builtin_amdgcn_cvt_pkrtz(e00, e01);
        fp16x2 b0 = __builtin_amdgcn_cvt_pkrtz(e02, e03);
        fp16x2 a1 = __builtin_amdgcn_cvt_pkrtz(e10, e11);
        fp16x2 b1 = __builtin_amdgcn_cvt_pkrtz(e12, e13);
        half4_ p0 = __builtin_bit_cast(half4_, __builtin_shufflevector(a0, b0, 0, 1, 2, 3));
        half4_ p1 = __builtin_bit_cast(half4_, __builtin_shufflevector(a1, b1, 0, 1, 2, 3));

        o0 = __builtin_amdgcn_mfma_f32_16x16x16f16(va, p0, o0, 0, 0, 0);
        o1 = __builtin_amdgcn_mfma_f32_16x16x16f16(va, p1, o1, 0, 0, 0);
    }

    float ls0 = __shfl(o0[0], 16 + ln16);
    float ls1 = __shfl(o1[0], 16 + ln16);

    float4 r0v = { 0.f, 0.f, 0.f, 0.f }, r1v = r0v;
    if (lane < 16) {
        {
            const size_t gi = (size_t)(b * L_ + q0 + ln16) * D_ + h * DH_;
            const float inv = 1.0f / ls0;
            const float4 e4 = *(const float4*)&encRaw[gi];
            r0v.x = fmaf(o0[0], inv, fmaf(e4.x, rsc[0], rsh[0]));
            r0v.y = fmaf(o0[1], inv, fmaf(e4.y, rsc[1], rsh[1]));
            r0v.z = fmaf(o0[2], inv, fmaf(e4.z, rsc[2], rsh[2]));
            r0v.w = fmaf(o0[3], inv, fmaf(e4.w, rsc[3], rsh[3]));
            *(float4*)&out[gi] = r0v;
        }
        {
            const size_t gi = (size_t)(b * L_ + q0 + 16 + ln16) * D_ + h * DH_;
            const float inv = 1.0f / ls1;
            const float4 e4 = *(const float4*)&encRaw[gi];
            r1v.x = fmaf(o1[0], inv, fmaf(e4.x, rsc[0], rsh[0]));
            r1v.y = fmaf(o1[1], inv, fmaf(e4.y, rsc[1], rsh[1]));
            r1v.z = fmaf(o1[2], inv, fmaf(e4.z, rsc[2], rsh[2]));
            r1v.w = fmaf(o1[3], inv, fmaf(e4.w, rsc[3], rsh[3]));
            *(float4*)&out[gi] = r1v;
        }
    }

    float s4[4] = { r0v.x + r1v.x, r0v.y + r1v.y, r0v.z + r1v.z, r0v.w + r1v.w };
    float q4[4] = { r0v.x*r0v.x + r1v.x*r1v.x, r0v.y*r0v.y + r1v.y*r1v.y,
                    r0v.z*r0v.z + r1v.z*r1v.z, r0v.w*r0v.w + r1v.w*r1v.w };
    #pragma unroll
    for (int d2 = 1; d2 <= 8; d2 <<= 1) {
        #pragma unroll
        for (int j = 0; j < 4; ++j) {
            s4[j] += __shfl_xor(s4[j], d2);
            q4[j] += __shfl_xor(q4[j], d2);
        }
    }
    if (lane == 0) {
        #pragma unroll
        for (int j = 0; j < 4; ++j) { wred[wv2][j] = s4[j]; wred[wv2][4 + j] = q4[j]; }
    }
    __syncthreads();
    if (t < 8) {
        float a = wred[0][t] + wred[1][t] + wred[2][t] + wred[3][t];
        const int row = (t >> 2) * 64 + 4 * h + (t & 3);
        partsOut[(size_t)row * PSTR_ + (b * 8 + qc)] = a;
    }
}

// ---------------------------------------------------------------------------
// Final BatchNorm apply.
// ---------------------------------------------------------------------------
__global__ __launch_bounds__(256) void bn_apply_kernel(
    const float* __restrict__ x, const float* __restrict__ parts,
    const float* __restrict__ gamma, const float* __restrict__ beta,
    float* __restrict__ y)
{
    __shared__ float fstats[128];
    const int t = threadIdx.x;
    if (t < 128) {
        const float* pr = parts + (size_t)t * PSTR_;
        float a = 0.f;
        for (int j = 0; j < 128; j += 4) {
            float4 v4 = *(const float4*)&pr[j];
            a += v4.x + v4.y + v4.z + v4.w;
        }
        fstats[t] = a;
    }
    __syncthreads();

    const int idx = blockIdx.x * 256 + t;
    const int c = (idx & 15) << 2;
    float4 xv = ((const float4*)x)[idx];
    float4 sm = *(const float4*)&fstats[c];
    float4 sq = *(const float4*)&fstats[64 + c];
    float4 g  = *(const float4*)&gamma[c];
    float4 be = *(const float4*)&beta[c];

    float mean[4] = {sm.x * INV_N_, sm.y * INV_N_, sm.z * INV_N_, sm.w * INV_N_};
    float ex2[4]  = {sq.x * INV_N_, sq.y * INV_N_, sq.z * INV_N_, sq.w * INV_N_};
    float xa[4] = {xv.x, xv.y, xv.z, xv.w};
    float ga[4] = {g.x, g.y, g.z, g.w};
    float ba[4] = {be.x, be.y, be.z, be.w};
    float ya[4];
    #pragma unroll
    for (int i = 0; i < 4; ++i) {
        float var = ex2[i] - mean[i] * mean[i];
        float rs = rsqrtf(var + EPS_);
        ya[i] = ga[i] * (xa[i] - mean[i]) * rs + ba[i];
    }
    float4 r = {ya[0], ya[1], ya[2], ya[3]};
    ((float4*)y)[idx] = r;
}

// ---------------------------------------------------------------------------
extern "C" void kernel_launch(void* const* d_in, const int* in_sizes, int n_in,
                              void* d_out, int out_size, void* d_ws, size_t ws_size,
                              hipStream_t stream)
{
    const float* x       = (const float*)d_in[0];
    const float* W_embed = (const float*)d_in[1];
    const float* b_embed = (const float*)d_in[2];
    const float* g0      = (const float*)d_in[3];
    const float* be0     = (const float*)d_in[4];
    const float* Wq      = (const float*)d_in[5];
    const float* bq      = (const float*)d_in[6];
    const float* Wk      = (const float*)d_in[7];
    const float* bk      = (const float*)d_in[8];
    const float* Wv      = (const float*)d_in[9];
    const float* bv      = (const float*)d_in[10];
    const float* g_attn  = (const float*)d_in[11];
    const float* be_attn = (const float*)d_in[12];
    const float* W1      = (const float*)d_in[13];
    const float* b1      = (const float*)d_in[14];
    const float* W2      = (const float*)d_in[15];
    const float* b2      = (const float*)d_in[16];
    const float* g_ff    = (const float*)d_in[17];
    const float* be_ff   = (const float*)d_in[18];

    float* ws     = (float*)d_ws;
    float* tmpA   = ws;                    // 524288 f32 (embed / ff2 out, pre-BN)
    float* tmpB   = ws + 524288;           // 524288 f32 (attn out, pre-BN)
    float* partsA = ws + 1048576;          // 16384 f32
    float* partsB = ws + 1064960;          // 16384 f32
    _Float16* hb  = (_Float16*)(ws + 1081344);
    _Float16* qh  = hb;                    // 524288 f16, head-major, x(0.5*log2e)
    _Float16* kh  = hb + 524288;           // head-major
    _Float16* vh  = hb + 1048576;          // head-major TRANSPOSED [b][h][dh][key]
    _Float16* h1  = hb + 1572864;          // 2097152 f16
    _Float16* wemh = hb + 3670016;         // weights f16, contiguous 49152
    _Float16* wqh  = wemh + 4096;
    _Float16* wkh  = wqh + 4096;
    _Float16* wvh  = wkh + 4096;
    _Float16* w1h  = wvh + 4096;
    _Float16* w2h  = w1h + 16384;
    float* out = (float*)d_out;

    const dim3 blk(256);

    prep_kernel<<<192, blk, 0, stream>>>(W_embed, Wq, Wk, Wv, W1, W2, wemh);
    embed_kernel<<<128, blk, 0, stream>>>(x, wemh, b_embed, tmpA, partsA);

    for (int s = 0; s < 3; ++s) {
        const float* gP  = (s == 0) ? g0  : g_ff;
        const float* beP = (s == 0) ? be0 : be_ff;
        qkv_kernel<<<dim3(128, 3), blk, 0, stream>>>(
            tmpA, wqh, bq, wkh, bk, wvh, bv, qh, kh, vh, partsA, gP, beP);
        attn_kernel<<<1024, blk, 0, stream>>>(
            qh, kh, vh, tmpA, tmpB, partsA, gP, beP, partsB);
        ff1_kernel<<<dim3(128, 4), blk, 0, stream>>>(
            tmpB, w1h, b1, h1, partsB, g_attn, be_attn);
        ff2_kernel<<<dim3(128, 2), blk, 0, stream>>>(
            h1, w2h, b2, tmpB, tmpA, partsB, g_attn, be_attn, partsA);
    }
    bn_apply_kernel<<<512, blk, 0, stream>>>(tmpA, partsA, g_ff, be_ff, out);
}